// Round 1
// baseline (117.352 us; speedup 1.0000x reference)
//
#include <hip/hip_runtime.h>

// RGCN HighMem: out[dst[e]] += feat[src[e]] @ W[etypes[e]]
// E=200000, N=50000, R=64, D=32.
//
// Round 6: remove the 6.4M fp32 global atomics (the suspected round-5
// floor). New structure:
//   prep:    featb/wpack pack (as round 5) + dst histogram (200k int atomics)
//   scan1/2: CSR offsets off[N+1] from the histogram (two tiny kernels)
//   compute: round-5 bucketing + MFMA tiles, but each edge claims a unique
//            dst-sorted slot (off[d] + atomicAdd(cur[d],1), 200k int atomics)
//            and PLAIN-STORES its 128B message row into msg[] (25.6 MB in
//            d_ws, L2/LLC-resident).
//   gather:  per node, sum the CONTIGUOUS msg rows [off[d], off[d+1]) and
//            store out — no atomics, fully coalesced, writes every node so
//            the out-memset is dropped.
// d_ws is free: the harness 0xAA-poisons it every iteration regardless
// (268 MB fill = the 43 us top dispatch in every round's profile).

#define D 32
#define NRELS 64
#define BLOCK 1024
#define WPB (BLOCK / 64)
#define GRID 256
#define MAXCHUNK 1024
#define MAXTILES (NRELS + MAXCHUNK / 16)

typedef __bf16 bf16x8 __attribute__((ext_vector_type(8)));
typedef float  f32x4  __attribute__((ext_vector_type(4)));

static __device__ __forceinline__ unsigned int f2b(float x) {
    unsigned int u = __float_as_uint(x);
    return (u + 0x7fffu + ((u >> 16) & 1u)) >> 16;   // RNE bf16
}

// ---- prep: feat -> bf16 rows; W -> B-fragment order; dst histogram -------

__global__ __launch_bounds__(256) void prep_kernel(
    const float* __restrict__ feat, const float* __restrict__ weight,
    const int* __restrict__ dst,
    unsigned short* __restrict__ featb,   // [N*32] bf16
    unsigned short* __restrict__ wpack,   // [64][2][64][8] bf16
    int* __restrict__ hist,               // [N] dst degree counts (pre-zeroed)
    int n_nodes, int E)
{
    int idx = blockIdx.x * 256 + threadIdx.x;
    int nfeat = n_nodes * 4;                    // one task = 8 elements
    int nw = NRELS * 2 * 64;
    if (idx < nfeat) {
        const float4* fp = (const float4*)(feat + (size_t)idx * 8);
        float4 a = fp[0], b = fp[1];
        uint4 o;
        o.x = f2b(a.x) | (f2b(a.y) << 16);
        o.y = f2b(a.z) | (f2b(a.w) << 16);
        o.z = f2b(b.x) | (f2b(b.y) << 16);
        o.w = f2b(b.z) | (f2b(b.w) << 16);
        ((uint4*)featb)[idx] = o;
    } else if (idx < nfeat + nw) {
        int t = idx - nfeat;
        int r = t >> 7, half = (t >> 6) & 1, lane = t & 63;
        int quad = lane >> 4, n = lane & 15;
        const float* W = weight + (size_t)r * (D * D) + half * 16 + n;
        uint4 o;
        unsigned int v[8];
        #pragma unroll
        for (int j = 0; j < 8; ++j) v[j] = f2b(W[(quad * 8 + j) * D]);
        o.x = v[0] | (v[1] << 16);
        o.y = v[2] | (v[3] << 16);
        o.z = v[4] | (v[5] << 16);
        o.w = v[6] | (v[7] << 16);
        ((uint4*)wpack)[t] = o;
    } else if (idx < nfeat + nw + E) {
        int e = idx - nfeat - nw;
        atomicAdd(&hist[dst[e]], 1);
    }
}

// ---- scan: exclusive prefix sum of hist[N] -> off[N+1] --------------------
// scan1: 1024 bins per block (256 thr x 4), writes partial offsets + bsum.

__global__ __launch_bounds__(256) void scan1_kernel(
    const int* __restrict__ hist, int* __restrict__ off,
    int* __restrict__ bsum, int N)
{
    __shared__ int wsum[4];
    int t = threadIdx.x;
    int idx = blockIdx.x * 1024 + t * 4;
    int4 v = {0, 0, 0, 0};
    if (idx + 3 < N) v = *(const int4*)(hist + idx);
    else {
        if (idx     < N) v.x = hist[idx];
        if (idx + 1 < N) v.y = hist[idx + 1];
        if (idx + 2 < N) v.z = hist[idx + 2];
        if (idx + 3 < N) v.w = hist[idx + 3];
    }
    int s0 = v.x, s1 = s0 + v.y, s2 = s1 + v.z, s3 = s2 + v.w;
    int x = s3;                       // wave-inclusive scan of thread totals
    #pragma unroll
    for (int o = 1; o < 64; o <<= 1) {
        int y = __shfl_up(x, o, 64);
        if ((t & 63) >= o) x += y;
    }
    if ((t & 63) == 63) wsum[t >> 6] = x;
    __syncthreads();
    int w = t >> 6;
    int wbase = 0;
    #pragma unroll
    for (int i = 0; i < 4; ++i) if (i < w) wbase += wsum[i];
    int excl = wbase + x - s3;        // exclusive prefix for this thread
    if (idx     < N) off[idx]     = excl;
    if (idx + 1 < N) off[idx + 1] = excl + s0;
    if (idx + 2 < N) off[idx + 2] = excl + s1;
    if (idx + 3 < N) off[idx + 3] = excl + s2;
    if (t == 255) bsum[blockIdx.x] = wbase + x;
}

// scan2: add sum of bsum[0..b) to block b's span; write sentinel off[N]=E.

__global__ __launch_bounds__(256) void scan2_kernel(
    int* __restrict__ off, const int* __restrict__ bsum,
    int N, int E, int nblk)
{
    __shared__ int sbase;
    int t = threadIdx.x;
    if (t < 64) {
        int v = (t < (int)blockIdx.x && t < nblk) ? bsum[t] : 0;
        #pragma unroll
        for (int o = 32; o > 0; o >>= 1) v += __shfl_down(v, o, 64);
        if (t == 0) sbase = v;
    }
    __syncthreads();
    int base = sbase;
    int idx = blockIdx.x * 1024 + t * 4;
    #pragma unroll
    for (int k = 0; k < 4; ++k)
        if (idx + k < N) off[idx + k] += base;
    if (blockIdx.x == 0 && t == 0) off[N] = E;
}

// ---- compute: bucket-by-relation + MFMA tiles + dst-sorted plain stores ---

__global__ __launch_bounds__(BLOCK, 4) void rgcn_compute_kernel(
    const unsigned short* __restrict__ featb,
    const unsigned short* __restrict__ wpack,
    const int* __restrict__ src,
    const int* __restrict__ dst,
    const int* __restrict__ etypes,
    const int* __restrict__ off,      // [N+1] CSR offsets by dst
    int* __restrict__ cur,            // [N] slot cursors (pre-zeroed)
    float* __restrict__ msg,          // [E][32] dst-sorted messages
    int E, int chunk)
{
    __shared__ int cnt[NRELS];
    __shared__ int offr[NRELS];
    __shared__ unsigned short list[MAXCHUNK];
    __shared__ unsigned short desc[MAXTILES];
    __shared__ int slot_sh[MAXCHUNK];
    __shared__ int ntile_sh;

    int tid = threadIdx.x;
    int gbase = blockIdx.x * chunk;

    if (tid < NRELS) cnt[tid] = 0;
    __syncthreads();

    // phase 1: bucket edges by relation + claim a unique dst-sorted slot
    int my_r = -1, my_rank = 0;
    if (tid < chunk && gbase + tid < E) {
        int e = gbase + tid;
        my_r = etypes[e];
        my_rank = atomicAdd(&cnt[my_r], 1);
        int d = dst[e];
        slot_sh[tid] = off[d] + atomicAdd(&cur[d], 1);
    }
    __syncthreads();

    // phase 2: wave 0 scans counts + builds relation-sorted tile descriptors
    if (tid < 64) {
        int c = cnt[tid];
        int x = c;
        #pragma unroll
        for (int o = 1; o < 64; o <<= 1) {
            int y = __shfl_up(x, o, 64);
            if (tid >= o) x += y;
        }
        offr[tid] = x - c;

        int nt = (c + 15) >> 4;
        int tx = nt;
        #pragma unroll
        for (int o = 1; o < 64; o <<= 1) {
            int y = __shfl_up(tx, o, 64);
            if (tid >= o) tx += y;
        }
        int tbase = tx - nt;
        for (int t = 0; t < nt; ++t)
            desc[tbase + t] = (unsigned short)((tid << 8) | t);
        if (tid == 63) ntile_sh = tx;
    }
    __syncthreads();

    if (my_r >= 0) list[offr[my_r] + my_rank] = (unsigned short)tid;
    int ntiles = ntile_sh;
    __syncthreads();

    // phase 3: contiguous tile runs per wave (relation-sorted)
    int wave = tid >> 6;
    int lane = tid & 63;
    int n    = lane & 15;
    int quad = lane >> 4;

    int per = (ntiles + WPB - 1) / WPB;
    int t0 = wave * per;
    int t1 = t0 + per; if (t1 > ntiles) t1 = ntiles;

    for (int ti = t0; ti < t1; ++ti) {
        int dsc = desc[ti];
        int r = dsc >> 8;
        int t = dsc & 255;
        int c = cnt[r];
        int mbase = t * 16;
        int mcnt = c - mbase; if (mcnt > 16) mcnt = 16;
        int lbase = offr[r] + mbase;

        // B fragments: one dwordx4 each from the packed buffer
        bf16x8 b0 = *(const bf16x8*)(wpack + ((size_t)(r * 2 + 0) * 64 + lane) * 8);
        bf16x8 b1 = *(const bf16x8*)(wpack + ((size_t)(r * 2 + 1) * 64 + lane) * 8);

        // A fragment: edge m = lane&15, k = quad*8+j — one dwordx4
        int mm = (n < mcnt) ? n : 0;
        int le = list[lbase + mm];
        int s  = src[gbase + le];
        bf16x8 a = *(const bf16x8*)(featb + (size_t)s * D + quad * 8);

        f32x4 z = {0.f, 0.f, 0.f, 0.f};
        f32x4 c0 = __builtin_amdgcn_mfma_f32_16x16x32_bf16(a, b0, z, 0, 0, 0);
        f32x4 c1 = __builtin_amdgcn_mfma_f32_16x16x32_bf16(a, b1, z, 0, 0, 0);

        // C: col = lane&15 (out col n), row = quad*4+v (edge in tile)
        // plain stores into the edge's dst-sorted msg row (no atomics)
        #pragma unroll
        for (int v = 0; v < 4; ++v) {
            int m2 = quad * 4 + v;
            if (m2 < mcnt) {
                int s2 = slot_sh[list[lbase + m2]];
                float* mr = msg + (size_t)s2 * D;
                mr[n]      = c0[v];
                mr[16 + n] = c1[v];
            }
        }
    }
}

// ---- gather: out[d] = sum of contiguous msg rows [off[d], off[d+1]) -------

__global__ __launch_bounds__(256) void gather_kernel(
    const float* __restrict__ msg, const int* __restrict__ off,
    float* __restrict__ out, int N)
{
    int d   = blockIdx.x * 8 + (threadIdx.x >> 5);
    int col = threadIdx.x & 31;
    if (d >= N) return;
    int b = off[d];
    int e = off[d + 1];
    float acc = 0.f;
    for (int j = b; j < e; ++j)
        acc += msg[(size_t)j * D + col];
    out[(size_t)d * D + col] = acc;
}

// ---- fallback (round-1 kernel) --------------------------------------------

__global__ __launch_bounds__(256) void rgcn_edge_kernel(
    const float* __restrict__ feat, const float* __restrict__ weight,
    const int* __restrict__ src, const int* __restrict__ dst,
    const int* __restrict__ etypes, float* __restrict__ out, int n_edges)
{
    int gid = blockIdx.x * blockDim.x + threadIdx.x;
    int e = gid >> 5;
    int o = gid & 31;
    if (e >= n_edges) return;
    int s = src[e], d = dst[e], r = etypes[e];
    const float* W = weight + (size_t)r * (D * D);
    float fv = feat[(size_t)s * D + o];
    float acc = 0.f;
    #pragma unroll
    for (int i = 0; i < D; ++i) {
        float fi = __shfl(fv, i, 32);
        acc = fmaf(fi, W[i * D + o], acc);
    }
    atomicAdd(&out[(size_t)d * D + o], acc);
}

// ---- launch ---------------------------------------------------------------

extern "C" void kernel_launch(void* const* d_in, const int* in_sizes, int n_in,
                              void* d_out, int out_size, void* d_ws, size_t ws_size,
                              hipStream_t stream) {
    const float* feat   = (const float*)d_in[0];
    const float* weight = (const float*)d_in[1];
    const int*   src    = (const int*)d_in[2];
    const int*   dst    = (const int*)d_in[3];
    const int*   etypes = (const int*)d_in[4];
    float*       out    = (float*)d_out;

    int N = in_sizes[0] / D;
    int R = in_sizes[1] / (D * D);
    int E = in_sizes[2];

    int chunk = (E + GRID - 1) / GRID;
    int nblk  = (N + 1023) / 1024;          // scan blocks (needs <= 64)

    // d_ws layout (all 16B aligned for N=50000, E=200000):
    size_t featb_elems = (size_t)N * D;                         // ushorts
    size_t wpack_elems = (size_t)NRELS * 2 * 64 * 8;            // ushorts
    size_t hist_off = (featb_elems + wpack_elems) * sizeof(unsigned short);
    size_t cur_off  = hist_off + (size_t)N * sizeof(int);
    size_t off_off  = cur_off  + (size_t)N * sizeof(int);
    size_t bsum_off = off_off  + ((size_t)N + 4) * sizeof(int); // N+1 + pad
    size_t msg_off  = bsum_off + 64 * sizeof(int);
    size_t need     = msg_off  + (size_t)E * D * sizeof(float);

    if (R != NRELS || chunk > MAXCHUNK || nblk > 64 ||
        (hist_off & 15) || ws_size < need) {
        hipMemsetAsync(d_out, 0, (size_t)out_size * sizeof(float), stream);
        long long total = (long long)E * 32;
        int grid = (int)((total + 255) / 256);
        rgcn_edge_kernel<<<grid, 256, 0, stream>>>(feat, weight, src, dst,
                                                   etypes, out, E);
        return;
    }

    unsigned short* featb = (unsigned short*)d_ws;
    unsigned short* wpack = featb + featb_elems;
    int*   hist = (int*)((char*)d_ws + hist_off);
    int*   cur  = (int*)((char*)d_ws + cur_off);
    int*   offp = (int*)((char*)d_ws + off_off);
    int*   bsum = (int*)((char*)d_ws + bsum_off);
    float* msg  = (float*)((char*)d_ws + msg_off);

    // zero hist + cur (contiguous, 2*N ints)
    hipMemsetAsync(hist, 0, (size_t)N * 2 * sizeof(int), stream);

    int prep_tasks = N * 4 + NRELS * 2 * 64 + E;
    int prep_grid = (prep_tasks + 255) / 256;
    prep_kernel<<<prep_grid, 256, 0, stream>>>(feat, weight, dst, featb, wpack,
                                               hist, N, E);

    scan1_kernel<<<nblk, 256, 0, stream>>>(hist, offp, bsum, N);
    scan2_kernel<<<nblk, 256, 0, stream>>>(offp, bsum, N, E, nblk);

    rgcn_compute_kernel<<<GRID, BLOCK, 0, stream>>>(featb, wpack, src, dst,
                                                    etypes, offp, cur, msg,
                                                    E, chunk);

    gather_kernel<<<(N + 7) / 8, 256, 0, stream>>>(msg, offp, out, N);
}

// Round 2
// 101.670 us; speedup vs baseline: 1.1542x; 1.1542x over previous
//
#include <hip/hip_runtime.h>

// RGCN HighMem: out[dst[e]] += feat[src[e]] @ W[etypes[e]]
// E=200000, N=50000, R=64, D=32.
//
// Round 7: round-6 (dst-sorted stores + gather) REGRESSED 94->117us while
// round 5's atomic scatter measured 94 -> the 6.4M fp32 atomics are NOT the
// floor (wave lanes land in 4x64B segments -> packed RMW at LLC). The cost
// is the in-kernel bucketing: 1024-thr block @ 1 block/CU, serial wave-0
// descriptor build behind full-block barriers, 76% tile fill, ~3 tiles/wave.
//
// New structure (atomic scatter KEPT):
//   memset out (6.4MB) + memset ctrl (320B)
//   prep_sort: featb/wpack pack (as round 5) + single-pass counting sort by
//              relation: per-block LDS histogram -> one global
//              atomicAdd(relcnt[r], c) per (block,rel) -> write edge ids into
//              fixed per-rel segments slist[r*CAP..] (CAP=4096 vs expected
//              3125+-55; overflow -> spill list, scalar fallback path).
//   compute:   zero LDS, zero barriers. 4096 waves; wave w owns rel r=w>>6
//              and 4 consecutive tiles -> B-fragments loaded ONCE into regs.
//              100% tile fill: 12.6k tiles (was 21k @ 76%).
// d_ws is free: harness 0xAA-poisons it every iteration regardless (268MB
// fill = the ~43us top dispatch in every round's profile).

#define D 32
#define NRELS 64
#define CAP 4096           // slist capacity per relation
#define TPR (CAP / 16)     // 256 tile slots per relation
#define SORTB 256          // sort blocks
#define CGRID 1024
#define CBLOCK 256

typedef __bf16 bf16x8 __attribute__((ext_vector_type(8)));
typedef float  f32x4  __attribute__((ext_vector_type(4)));

static __device__ __forceinline__ unsigned int f2b(float x) {
    unsigned int u = __float_as_uint(x);
    return (u + 0x7fffu + ((u >> 16) & 1u)) >> 16;   // RNE bf16
}

// ---- prep + counting sort by relation ------------------------------------

__global__ __launch_bounds__(256) void prep_sort_kernel(
    const float* __restrict__ feat, const float* __restrict__ weight,
    const int* __restrict__ etypes,
    unsigned short* __restrict__ featb,   // [N*32] bf16
    unsigned short* __restrict__ wpack,   // [64][2][64][8] bf16
    int* __restrict__ relcnt,             // [64] (pre-zeroed)
    int* __restrict__ spillcnt,           // [1]  (pre-zeroed)
    int* __restrict__ slist,              // [64][CAP] edge ids
    int* __restrict__ spill,              // [E] overflow edge ids
    int n_nodes, int E, int nbf, int chunk)
{
    int b = blockIdx.x, tid = threadIdx.x;

    if (b < nbf) {                         // featb pack: one task = 8 elems
        int idx = b * 256 + tid;
        if (idx < n_nodes * 4) {
            const float4* fp = (const float4*)(feat + (size_t)idx * 8);
            float4 a = fp[0], c = fp[1];
            uint4 o;
            o.x = f2b(a.x) | (f2b(a.y) << 16);
            o.y = f2b(a.z) | (f2b(a.w) << 16);
            o.z = f2b(c.x) | (f2b(c.y) << 16);
            o.w = f2b(c.z) | (f2b(c.w) << 16);
            ((uint4*)featb)[idx] = o;
        }
        return;
    }
    if (b < nbf + 32) {                    // wpack: 8192 tasks exactly
        int t = (b - nbf) * 256 + tid;
        int r = t >> 7, half = (t >> 6) & 1, lane = t & 63;
        int quad = lane >> 4, n = lane & 15;
        const float* W = weight + (size_t)r * (D * D) + half * 16 + n;
        uint4 o;
        unsigned int v[8];
        #pragma unroll
        for (int j = 0; j < 8; ++j) v[j] = f2b(W[(quad * 8 + j) * D]);
        o.x = v[0] | (v[1] << 16);
        o.y = v[2] | (v[3] << 16);
        o.z = v[4] | (v[5] << 16);
        o.w = v[6] | (v[7] << 16);
        ((uint4*)wpack)[t] = o;
        return;
    }

    // sort block: chunk edges, LDS histogram + rank, then global segment claim
    int sb = b - nbf - 32;
    __shared__ int bins[NRELS];
    __shared__ int sbase[NRELS];
    if (tid < NRELS) bins[tid] = 0;
    __syncthreads();

    int cb = sb * chunk;
    int ce = cb + chunk; if (ce > E) ce = E;
    int kit = (chunk + 255) >> 8;          // <= 4 (host guard chunk<=1024)

    int myr[4], myk[4];
    #pragma unroll
    for (int k = 0; k < 4; ++k) {
        myr[k] = -1;
        int e = cb + k * 256 + tid;
        if (k < kit && e < ce) {
            myr[k] = etypes[e];
            myk[k] = atomicAdd(&bins[myr[k]], 1);
        }
    }
    __syncthreads();

    if (tid < NRELS) {
        int c = bins[tid];
        sbase[tid] = c ? atomicAdd(&relcnt[tid], c) : 0;
    }
    __syncthreads();

    #pragma unroll
    for (int k = 0; k < 4; ++k) {
        if (myr[k] >= 0) {
            int e = cb + k * 256 + tid;
            int r = myr[k];
            int p = sbase[r] + myk[k];
            if (p < CAP) slist[r * CAP + p] = e;
            else { int sp = atomicAdd(spillcnt, 1); spill[sp] = e; }
        }
    }
}

// ---- compute: perfect MFMA tiles, B in registers, atomic scatter ----------

__global__ __launch_bounds__(256) void rgcn_compute_kernel(
    const unsigned short* __restrict__ featb,
    const unsigned short* __restrict__ wpack,
    const int* __restrict__ src,
    const int* __restrict__ dst,
    const int* __restrict__ etypes,
    const int* __restrict__ slist,
    const int* __restrict__ relcnt,
    const int* __restrict__ spill,
    const int* __restrict__ spillcnt,
    const float* __restrict__ feat,
    const float* __restrict__ weight,
    float* __restrict__ out, int E)
{
    int tid  = threadIdx.x;
    int wg   = blockIdx.x * (CBLOCK / 64) + (tid >> 6);   // 0..4095
    int lane = tid & 63;
    int n    = lane & 15;
    int quad = lane >> 4;

    int r  = wg >> 6;                      // one relation per wave
    int t0 = (wg & 63) * (TPR / 64);       // 4 consecutive tile slots

    int cnt = relcnt[r]; if (cnt > CAP) cnt = CAP;
    int ntr = (cnt + 15) >> 4;
    int tend = t0 + (TPR / 64); if (tend > ntr) tend = ntr;

    if (t0 < tend) {
        // B fragments loaded once per wave, reused across all tiles
        bf16x8 b0 = *(const bf16x8*)(wpack + ((size_t)(r * 2 + 0) * 64 + lane) * 8);
        bf16x8 b1 = *(const bf16x8*)(wpack + ((size_t)(r * 2 + 1) * 64 + lane) * 8);

        for (int t = t0; t < tend; ++t) {
            int tb   = t * 16;
            int mcnt = cnt - tb; if (mcnt > 16) mcnt = 16;
            int base = r * CAP + tb;

            int mm = (n < mcnt) ? n : (mcnt - 1);
            int e  = slist[base + mm];     // lane m holds edge m of the tile
            int s  = src[e];
            int d  = dst[e];

            bf16x8 a = *(const bf16x8*)(featb + (size_t)s * D + quad * 8);

            f32x4 z = {0.f, 0.f, 0.f, 0.f};
            f32x4 c0 = __builtin_amdgcn_mfma_f32_16x16x32_bf16(a, b0, z, 0, 0, 0);
            f32x4 c1 = __builtin_amdgcn_mfma_f32_16x16x32_bf16(a, b1, z, 0, 0, 0);

            // C: col = lane&15, row = quad*4+v (edge in tile)
            #pragma unroll
            for (int v = 0; v < 4; ++v) {
                int m2 = quad * 4 + v;
                if (m2 < mcnt) {
                    int d2 = __shfl(d, m2, 16);   // edge m2's dst from lane m2
                    atomicAdd(out + (size_t)d2 * D + n,      c0[v]);
                    atomicAdd(out + (size_t)d2 * D + 16 + n, c1[v]);
                }
            }
        }
    }

    // spill path (normally empty): scalar per-edge fp32
    int ns = *spillcnt;
    if (ns > 0) {
        if (ns > E) ns = E;
        int gsz = gridDim.x * blockDim.x;
        for (int idx = blockIdx.x * CBLOCK + tid; idx < ns * 32; idx += gsz) {
            int e = spill[idx >> 5];
            int o = idx & 31;
            int s = src[e], d = dst[e], rr = etypes[e];
            const float* W = weight + (size_t)rr * (D * D);
            float fv = feat[(size_t)s * D + o];
            float acc = 0.f;
            #pragma unroll
            for (int i = 0; i < D; ++i)
                acc = fmaf(__shfl(fv, i, 32), W[i * D + o], acc);
            atomicAdd(&out[(size_t)d * D + o], acc);
        }
    }
}

// ---- fallback (round-1 kernel) --------------------------------------------

__global__ __launch_bounds__(256) void rgcn_edge_kernel(
    const float* __restrict__ feat, const float* __restrict__ weight,
    const int* __restrict__ src, const int* __restrict__ dst,
    const int* __restrict__ etypes, float* __restrict__ out, int n_edges)
{
    int gid = blockIdx.x * blockDim.x + threadIdx.x;
    int e = gid >> 5;
    int o = gid & 31;
    if (e >= n_edges) return;
    int s = src[e], d = dst[e], r = etypes[e];
    const float* W = weight + (size_t)r * (D * D);
    float fv = feat[(size_t)s * D + o];
    float acc = 0.f;
    #pragma unroll
    for (int i = 0; i < D; ++i) {
        float fi = __shfl(fv, i, 32);
        acc = fmaf(fi, W[i * D + o], acc);
    }
    atomicAdd(&out[(size_t)d * D + o], acc);
}

// ---- launch ---------------------------------------------------------------

extern "C" void kernel_launch(void* const* d_in, const int* in_sizes, int n_in,
                              void* d_out, int out_size, void* d_ws, size_t ws_size,
                              hipStream_t stream) {
    const float* feat   = (const float*)d_in[0];
    const float* weight = (const float*)d_in[1];
    const int*   src    = (const int*)d_in[2];
    const int*   dst    = (const int*)d_in[3];
    const int*   etypes = (const int*)d_in[4];
    float*       out    = (float*)d_out;

    int N = in_sizes[0] / D;
    int R = in_sizes[1] / (D * D);
    int E = in_sizes[2];

    int chunk = (E + SORTB - 1) / SORTB;   // per sort block
    int nbf   = (N * 4 + 255) / 256;       // featb pack blocks

    // d_ws layout (16B aligned throughout for N=50000):
    size_t featb_elems = (size_t)N * D;                   // ushorts
    size_t wpack_elems = (size_t)NRELS * 2 * 64 * 8;      // ushorts (65536)
    size_t ctrl_off  = (featb_elems + wpack_elems) * sizeof(unsigned short);
    size_t slist_off = ctrl_off + 80 * sizeof(int);       // relcnt[64]+spillcnt+pad
    size_t spill_off = slist_off + (size_t)NRELS * CAP * sizeof(int);
    size_t need      = spill_off + (size_t)E * sizeof(int);

    if (R != NRELS || chunk > 1024 || (ctrl_off & 15) || ws_size < need) {
        hipMemsetAsync(d_out, 0, (size_t)out_size * sizeof(float), stream);
        long long total = (long long)E * 32;
        int grid = (int)((total + 255) / 256);
        rgcn_edge_kernel<<<grid, 256, 0, stream>>>(feat, weight, src, dst,
                                                   etypes, out, E);
        return;
    }

    unsigned short* featb = (unsigned short*)d_ws;
    unsigned short* wpack = featb + featb_elems;
    int* relcnt   = (int*)((char*)d_ws + ctrl_off);
    int* spillcnt = relcnt + 64;
    int* slist    = (int*)((char*)d_ws + slist_off);
    int* spill    = (int*)((char*)d_ws + spill_off);

    hipMemsetAsync(d_out, 0, (size_t)out_size * sizeof(float), stream);
    hipMemsetAsync(relcnt, 0, 80 * sizeof(int), stream);

    int prep_grid = nbf + 32 + SORTB;
    prep_sort_kernel<<<prep_grid, 256, 0, stream>>>(
        feat, weight, etypes, featb, wpack, relcnt, spillcnt, slist, spill,
        N, E, nbf, chunk);

    rgcn_compute_kernel<<<CGRID, CBLOCK, 0, stream>>>(
        featb, wpack, src, dst, etypes, slist, relcnt, spill, spillcnt,
        feat, weight, out, E);
}

// Round 3
// 93.149 us; speedup vs baseline: 1.2598x; 1.0915x over previous
//
#include <hip/hip_runtime.h>

// RGCN HighMem: out[dst[e]] += feat[src[e]] @ W[etypes[e]]
// E=200000, N=50000, R=64, D=32.
//
// Round 8: DISPATCH-COUNT theory. R6 (+3 dispatches) = +23us, R7
// (+1 dispatch, compute strictly better-structured) = +7.4us -> each extra
// graph dispatch costs ~7us; compute restructures were neutral-to-negative.
// So: revert to the measured-best R5 structure (94.3us) EXACTLY, and cut
// 3 dispatches -> 2 by folding the out-memset into prep as a third task
// range (400k uint4 zero-stores). Fused kernel untouched from R5.
// d_ws is free: harness 0xAA-poisons it every iteration regardless (268MB
// fill = the ~43us top dispatch in every round's profile).

#define D 32
#define NRELS 64
#define BLOCK 1024
#define WPB (BLOCK / 64)
#define GRID 256
#define MAXCHUNK 1024
#define MAXTILES (NRELS + MAXCHUNK / 16)

typedef __bf16 bf16x8 __attribute__((ext_vector_type(8)));
typedef float  f32x4  __attribute__((ext_vector_type(4)));

static __device__ __forceinline__ unsigned int f2b(float x) {
    unsigned int u = __float_as_uint(x);
    return (u + 0x7fffu + ((u >> 16) & 1u)) >> 16;   // RNE bf16
}

// ---- prep: feat -> bf16 rows; W -> B-fragment order; zero out -------------

__global__ __launch_bounds__(256) void prep_kernel(
    const float* __restrict__ feat, const float* __restrict__ weight,
    unsigned short* __restrict__ featb,   // [N*32] bf16
    unsigned short* __restrict__ wpack,   // [64][2][64][8] bf16
    float* __restrict__ out,              // zeroed here (atomic target)
    int n_nodes, int nzero)
{
    int idx = blockIdx.x * 256 + threadIdx.x;
    int nfeat = n_nodes * 4;                    // one task = 8 elements
    int nw = NRELS * 2 * 64;
    if (idx < nfeat) {
        const float4* fp = (const float4*)(feat + (size_t)idx * 8);
        float4 a = fp[0], b = fp[1];
        uint4 o;
        o.x = f2b(a.x) | (f2b(a.y) << 16);
        o.y = f2b(a.z) | (f2b(a.w) << 16);
        o.z = f2b(b.x) | (f2b(b.y) << 16);
        o.w = f2b(b.z) | (f2b(b.w) << 16);
        ((uint4*)featb)[idx] = o;
    } else if (idx < nfeat + nw) {
        int t = idx - nfeat;
        int r = t >> 7, half = (t >> 6) & 1, lane = t & 63;
        int quad = lane >> 4, n = lane & 15;
        const float* W = weight + (size_t)r * (D * D) + half * 16 + n;
        uint4 o;
        unsigned int v[8];
        #pragma unroll
        for (int j = 0; j < 8; ++j) v[j] = f2b(W[(quad * 8 + j) * D]);
        o.x = v[0] | (v[1] << 16);
        o.y = v[2] | (v[3] << 16);
        o.z = v[4] | (v[5] << 16);
        o.w = v[6] | (v[7] << 16);
        ((uint4*)wpack)[t] = o;
    } else if (idx < nfeat + nw + nzero) {
        int t = idx - nfeat - nw;
        uint4 z = {0u, 0u, 0u, 0u};
        ((uint4*)out)[t] = z;
    }
}

// ---- main: bucket-by-relation + MFMA tiles + atomic scatter ---------------
// (byte-identical to the 94.3us round-5 kernel)

__global__ __launch_bounds__(BLOCK, 4) void rgcn_fused_kernel(
    const unsigned short* __restrict__ featb,
    const unsigned short* __restrict__ wpack,
    const int* __restrict__ src,
    const int* __restrict__ dst,
    const int* __restrict__ etypes,
    float* __restrict__ out,
    int E, int chunk)
{
    __shared__ int cnt[NRELS];
    __shared__ int off[NRELS];
    __shared__ unsigned short list[MAXCHUNK];
    __shared__ unsigned short desc[MAXTILES];
    __shared__ int ntile_sh;

    int tid = threadIdx.x;
    int gbase = blockIdx.x * chunk;

    if (tid < NRELS) cnt[tid] = 0;
    __syncthreads();

    // phase 1: bucket edges by relation
    int my_r = -1, my_rank = 0;
    if (tid < chunk && gbase + tid < E) {
        my_r = etypes[gbase + tid];
        my_rank = atomicAdd(&cnt[my_r], 1);
    }
    __syncthreads();

    // phase 2: wave 0 scans counts + builds relation-sorted tile descriptors
    if (tid < 64) {
        int c = cnt[tid];
        int x = c;
        #pragma unroll
        for (int o = 1; o < 64; o <<= 1) {
            int y = __shfl_up(x, o, 64);
            if (tid >= o) x += y;
        }
        off[tid] = x - c;

        int nt = (c + 15) >> 4;
        int tx = nt;
        #pragma unroll
        for (int o = 1; o < 64; o <<= 1) {
            int y = __shfl_up(tx, o, 64);
            if (tid >= o) tx += y;
        }
        int tbase = tx - nt;
        for (int t = 0; t < nt; ++t)
            desc[tbase + t] = (unsigned short)((tid << 8) | t);
        if (tid == 63) ntile_sh = tx;
    }
    __syncthreads();

    if (my_r >= 0) list[off[my_r] + my_rank] = (unsigned short)tid;
    int ntiles = ntile_sh;
    __syncthreads();

    // phase 3: contiguous tile runs per wave (relation-sorted)
    int wave = tid >> 6;
    int lane = tid & 63;
    int n    = lane & 15;
    int quad = lane >> 4;

    int per = (ntiles + WPB - 1) / WPB;
    int t0 = wave * per;
    int t1 = t0 + per; if (t1 > ntiles) t1 = ntiles;

    for (int ti = t0; ti < t1; ++ti) {
        int dsc = desc[ti];
        int r = dsc >> 8;
        int t = dsc & 255;
        int c = cnt[r];
        int mbase = t * 16;
        int mcnt = c - mbase; if (mcnt > 16) mcnt = 16;
        int lbase = off[r] + mbase;

        // B fragments: one dwordx4 each from the packed buffer
        bf16x8 b0 = *(const bf16x8*)(wpack + ((size_t)(r * 2 + 0) * 64 + lane) * 8);
        bf16x8 b1 = *(const bf16x8*)(wpack + ((size_t)(r * 2 + 1) * 64 + lane) * 8);

        // A fragment: edge m = lane&15, k = quad*8+j — one dwordx4
        int mm = (n < mcnt) ? n : 0;
        int le = list[lbase + mm];
        int s  = src[gbase + le];
        bf16x8 a = *(const bf16x8*)(featb + (size_t)s * D + quad * 8);

        f32x4 z = {0.f, 0.f, 0.f, 0.f};
        f32x4 c0 = __builtin_amdgcn_mfma_f32_16x16x32_bf16(a, b0, z, 0, 0, 0);
        f32x4 c1 = __builtin_amdgcn_mfma_f32_16x16x32_bf16(a, b1, z, 0, 0, 0);

        // C: col = lane&15 (out col n), row = quad*4+v (edge in tile)
        #pragma unroll
        for (int v = 0; v < 4; ++v) {
            int m2 = quad * 4 + v;
            if (m2 < mcnt) {
                int le2 = list[lbase + m2];
                int d = dst[gbase + le2];
                atomicAdd(out + (size_t)d * D + n,      c0[v]);
                atomicAdd(out + (size_t)d * D + 16 + n, c1[v]);
            }
        }
    }
}

// ---- fallback (round-1 kernel) --------------------------------------------

__global__ __launch_bounds__(256) void rgcn_edge_kernel(
    const float* __restrict__ feat, const float* __restrict__ weight,
    const int* __restrict__ src, const int* __restrict__ dst,
    const int* __restrict__ etypes, float* __restrict__ out, int n_edges)
{
    int gid = blockIdx.x * blockDim.x + threadIdx.x;
    int e = gid >> 5;
    int o = gid & 31;
    if (e >= n_edges) return;
    int s = src[e], d = dst[e], r = etypes[e];
    const float* W = weight + (size_t)r * (D * D);
    float fv = feat[(size_t)s * D + o];
    float acc = 0.f;
    #pragma unroll
    for (int i = 0; i < D; ++i) {
        float fi = __shfl(fv, i, 32);
        acc = fmaf(fi, W[i * D + o], acc);
    }
    atomicAdd(&out[(size_t)d * D + o], acc);
}

// ---- launch ---------------------------------------------------------------

extern "C" void kernel_launch(void* const* d_in, const int* in_sizes, int n_in,
                              void* d_out, int out_size, void* d_ws, size_t ws_size,
                              hipStream_t stream) {
    const float* feat   = (const float*)d_in[0];
    const float* weight = (const float*)d_in[1];
    const int*   src    = (const int*)d_in[2];
    const int*   dst    = (const int*)d_in[3];
    const int*   etypes = (const int*)d_in[4];
    float*       out    = (float*)d_out;

    int N = in_sizes[0] / D;
    int R = in_sizes[1] / (D * D);
    int E = in_sizes[2];

    int chunk = (E + GRID - 1) / GRID;
    size_t featb_elems = (size_t)N * D;
    size_t need = (featb_elems + (size_t)NRELS * 2 * 64 * 8) * sizeof(unsigned short);

    if (R != NRELS || chunk > MAXCHUNK || ws_size < need || (out_size & 3)) {
        hipMemsetAsync(d_out, 0, (size_t)out_size * sizeof(float), stream);
        long long total = (long long)E * 32;
        int grid = (int)((total + 255) / 256);
        rgcn_edge_kernel<<<grid, 256, 0, stream>>>(feat, weight, src, dst,
                                                   etypes, out, E);
        return;
    }

    unsigned short* featb = (unsigned short*)d_ws;
    unsigned short* wpack = featb + featb_elems;   // N*64 bytes offset, 16B-aligned

    int nzero = out_size / 4;                      // uint4 zero-stores
    int prep_tasks = N * 4 + NRELS * 2 * 64 + nzero;
    int prep_grid = (prep_tasks + 255) / 256;
    prep_kernel<<<prep_grid, 256, 0, stream>>>(feat, weight, featb, wpack,
                                               out, N, nzero);

    rgcn_fused_kernel<<<GRID, BLOCK, 0, stream>>>(featb, wpack, src, dst,
                                                  etypes, out, E, chunk);
}